// Round 5
// baseline (140.338 us; speedup 1.0000x reference)
//
#include <hip/hip_runtime.h>
#include <hip/hip_fp16.h>
#include <math.h>

#define DF 32
#define EPSF 1e-12f
#define PB 256            // nodes per coarse bucket
#define PB_SHIFT 8
#define CAP 9472          // edge capacity per bucket (mean ~8163, +14 sigma)
#define CHUNK 4096        // edges per passA block
#define EPT 16            // edges per thread (CHUNK/256)

// ---- Pass A: coarse-bucket edges by target node, coalesced packed writes.
// packed record: b(8) | i_local(8) | j(16)   [needs n_nodes <= 65536, nb <= 256]
__global__ __launch_bounds__(256) void k_passA(
    const int* __restrict__ ii, const int* __restrict__ jj,
    int* __restrict__ gcount, unsigned int* __restrict__ bucketed, int ne, int nb) {
  __shared__ int hist[256];
  __shared__ int histc[256];
  __shared__ int bb[256];
  __shared__ unsigned int stage[CHUNK];
  int t = threadIdx.x;
  hist[t] = 0;
  __syncthreads();

  int base = blockIdx.x * CHUNK;
  unsigned int pk[EPT];
  int rk[EPT];
#pragma unroll
  for (int k = 0; k < EPT; ++k) {
    int e = base + t + k * 256;
    if (e < ne) {
      int i = ii[e], j = jj[e];
      int b = i >> PB_SHIFT;
      pk[k] = ((unsigned)b << 24) | ((unsigned)(i & (PB - 1)) << 16) | (unsigned)j;
      rk[k] = atomicAdd(&hist[b], 1);
    } else {
      rk[k] = -1;
    }
  }
  __syncthreads();
  histc[t] = hist[t];
  __syncthreads();
  int bv = 0;
  if (t < nb && histc[t] > 0) bv = atomicAdd(&gcount[t], histc[t]);
  bb[t] = bv;
  // inclusive scan of hist[0..255]
  for (int s = 1; s < 256; s <<= 1) {
    int v = 0;
    if (t >= s) v = hist[t - s];
    __syncthreads();
    if (t >= s) hist[t] += v;
    __syncthreads();
  }
#pragma unroll
  for (int k = 0; k < EPT; ++k) {
    if (rk[k] >= 0) {
      int b = pk[k] >> 24;
      stage[hist[b] - histc[b] + rk[k]] = pk[k];
    }
  }
  __syncthreads();
  int bcnt = ne - base;
  if (bcnt > CHUNK) bcnt = CHUNK;
  for (int p = t; p < bcnt; p += 256) {
    unsigned int v = stage[p];
    int b = v >> 24;
    int excl = hist[b] - histc[b];
    bucketed[(size_t)b * CAP + bb[b] + (p - excl)] = v;
  }
}

// ---- exclusive prefix over bucket counts (single block, 256 threads)
__global__ __launch_bounds__(256) void k_bprefix(const int* __restrict__ gcount,
                                                 int* __restrict__ bstart, int nb) {
  __shared__ int sc[256];
  int t = threadIdx.x;
  sc[t] = (t < nb) ? gcount[t] : 0;
  __syncthreads();
  int orig = sc[t];
  for (int s = 1; s < 256; s <<= 1) {
    int v = 0;
    if (t >= s) v = sc[t - s];
    __syncthreads();
    if (t >= s) sc[t] += v;
    __syncthreads();
  }
  if (t < nb) bstart[t] = sc[t] - orig;
  if (t == nb - 1) bstart[nb] = sc[t];
}

// ---- Pass B: per coarse bucket, build CSR (sortedj + deg + curend) and
// LDS-aggregated degree histogram for the later degree sort.
__global__ __launch_bounds__(256) void k_passB(
    const unsigned int* __restrict__ bucketed, const int* __restrict__ gcount,
    const int* __restrict__ bstart, int* __restrict__ sortedj,
    int* __restrict__ deg, int* __restrict__ curend,
    int* __restrict__ dhist, int n_nodes) {
  __shared__ int lh[PB];
  __shared__ int sc[256];
  __shared__ int lcur[PB];
  __shared__ int dh[256];
  int b = blockIdx.x;
  int t = threadIdx.x;
  int cnt = gcount[b];
  int gbase = bstart[b];
  const unsigned int* src = bucketed + (size_t)b * CAP;
  lh[t] = 0;
  dh[t] = 0;
  __syncthreads();
  for (int p = t; p < cnt; p += 256) {
    int il = (src[p] >> 16) & (PB - 1);
    atomicAdd(&lh[il], 1);
  }
  __syncthreads();
  int a = lh[t];
  sc[t] = a;
  __syncthreads();
  for (int s = 1; s < 256; s <<= 1) {
    int v = 0;
    if (t >= s) v = sc[t - s];
    __syncthreads();
    if (t >= s) sc[t] += v;
    __syncthreads();
  }
  int excl = sc[t] - a;
  lcur[t] = excl;
  int node = b * PB + t;
  if (node < n_nodes) {
    deg[node] = a;
    curend[node] = gbase + excl + a;
    atomicAdd(&dh[a < 255 ? a : 255], 1);
  }
  __syncthreads();
  if (dh[t] > 0) atomicAdd(&dhist[t], dh[t]);
  for (int p = t; p < cnt; p += 256) {
    unsigned int v = src[p];
    int il = (v >> 16) & (PB - 1);
    int pos = atomicAdd(&lcur[il], 1);
    sortedj[gbase + pos] = (int)(v & 0xFFFFu);
  }
}

// ---- exclusive prefix over degree histogram -> dcur (scatter cursors)
__global__ __launch_bounds__(256) void k_dprefix(const int* __restrict__ dhist,
                                                 int* __restrict__ dcur) {
  __shared__ int sc[256];
  int t = threadIdx.x;
  int orig = dhist[t];
  sc[t] = orig;
  __syncthreads();
  for (int s = 1; s < 256; s <<= 1) {
    int v = 0;
    if (t >= s) v = sc[t - s];
    __syncthreads();
    if (t >= s) sc[t] += v;
    __syncthreads();
  }
  dcur[t] = sc[t] - orig;
}

// ---- scatter node ids into degree-sorted order (LDS-aggregated reservations)
__global__ __launch_bounds__(256) void k_dscatter(const int* __restrict__ deg,
                                                  int* __restrict__ dcur,
                                                  int* __restrict__ perm, int n) {
  __shared__ int h[256];
  __shared__ int base[256];
  int t = threadIdx.x;
  int node = blockIdx.x * 256 + t;
  h[t] = 0;
  __syncthreads();
  int bin = -1, rank = 0;
  if (node < n) {
    int d = deg[node];
    bin = d < 255 ? d : 255;
    rank = atomicAdd(&h[bin], 1);
  }
  __syncthreads();
  if (h[t] > 0) base[t] = atomicAdd(&dcur[t], h[t]);
  __syncthreads();
  if (node < n) perm[base[bin] + rank] = node;
}

// ---- x (f32) -> xh (fp16), 8 elems/thread, coalesced
__global__ __launch_bounds__(256) void k_tohalf(const float* __restrict__ x,
                                                __half* __restrict__ xh, int n8) {
  int t = blockIdx.x * blockDim.x + threadIdx.x;
  if (t < n8) {
    float4 a = ((const float4*)x)[2 * t];
    float4 b = ((const float4*)x)[2 * t + 1];
    union { __half2 h[4]; float4 f; } u;
    u.h[0] = __floats2half2_rn(a.x, a.y);
    u.h[1] = __floats2half2_rn(a.z, a.w);
    u.h[2] = __floats2half2_rn(b.x, b.y);
    u.h[3] = __floats2half2_rn(b.z, b.w);
    ((float4*)xh)[t] = u.f;
  }
}

// ---- 16 nodes/wave, 4 lanes/node, lane owns 8 features. No cross-lane reduce.
// fp16 packed accumulate (v_pk_add_f16); fused (x - mean)^2 -> yh (fp16).
__global__ __launch_bounds__(256) void k_meansq(
    const int* __restrict__ perm, const int* __restrict__ sortedj,
    const int* __restrict__ curend, const int* __restrict__ deg,
    const __half* __restrict__ xh, const float* __restrict__ x,
    __half* __restrict__ yh, int n) {
  int wv = (int)((blockIdx.x * blockDim.x + threadIdx.x) >> 6);
  int lane = threadIdx.x & 63;
  int g = lane >> 2;   // node slot 0..15
  int c = lane & 3;    // feature quad (8 features)
  int ni = wv * 16 + g;
  bool valid = (ni < n);
  int w = valid ? perm[ni] : 0;
  int dg = valid ? deg[w] : 0;
  int end = valid ? curend[w] : 0;
  int start = end - dg;
  __half2 a0 = {}, a1 = {}, a2 = {}, a3 = {};
  int co = c * 8;
  for (int s = start; s < end; ++s) {
    int j = sortedj[s];
    float4 v = *(const float4*)&xh[j * DF + co];
    const __half2* h = (const __half2*)&v;
    a0 = __hadd2(a0, h[0]);
    a1 = __hadd2(a1, h[1]);
    a2 = __hadd2(a2, h[2]);
    a3 = __hadd2(a3, h[3]);
  }
  if (valid) {
    float inv = 1.0f / fmaxf((float)dg, 1.0f);
    float2 m0 = __half22float2(a0);
    float2 m1 = __half22float2(a1);
    float2 m2 = __half22float2(a2);
    float2 m3 = __half22float2(a3);
    float4 xa = *(const float4*)&x[w * DF + co];
    float4 xb = *(const float4*)&x[w * DF + co + 4];
    float d0 = xa.x - m0.x * inv;
    float d1 = xa.y - m0.y * inv;
    float d2 = xa.z - m1.x * inv;
    float d3 = xa.w - m1.y * inv;
    float d4 = xb.x - m2.x * inv;
    float d5 = xb.y - m2.y * inv;
    float d6 = xb.z - m3.x * inv;
    float d7 = xb.w - m3.y * inv;
    union { __half2 h[4]; float4 f; } u;
    u.h[0] = __floats2half2_rn(d0 * d0, d1 * d1);
    u.h[1] = __floats2half2_rn(d2 * d2, d3 * d3);
    u.h[2] = __floats2half2_rn(d4 * d4, d5 * d5);
    u.h[3] = __floats2half2_rn(d6 * d6, d7 * d7);
    *(float4*)&yh[w * DF + co] = u.f;
  }
}

// ---- same shape on yh; f32 accumulate (non-negative values); fused epilogue.
__global__ __launch_bounds__(256) void k_varfinal(
    const int* __restrict__ perm, const int* __restrict__ sortedj,
    const int* __restrict__ curend, const int* __restrict__ deg,
    const __half* __restrict__ yh, const float* __restrict__ x,
    float* __restrict__ out, int n) {
  int wv = (int)((blockIdx.x * blockDim.x + threadIdx.x) >> 6);
  int lane = threadIdx.x & 63;
  int g = lane >> 2;
  int c = lane & 3;
  int ni = wv * 16 + g;
  bool valid = (ni < n);
  int w = valid ? perm[ni] : 0;
  int dg = valid ? deg[w] : 0;
  int end = valid ? curend[w] : 0;
  int start = end - dg;
  float acc0 = 0.f, acc1 = 0.f, acc2 = 0.f, acc3 = 0.f;
  float acc4 = 0.f, acc5 = 0.f, acc6 = 0.f, acc7 = 0.f;
  int co = c * 8;
  for (int s = start; s < end; ++s) {
    int j = sortedj[s];
    float4 v = *(const float4*)&yh[j * DF + co];
    const __half2* h = (const __half2*)&v;
    float2 f0 = __half22float2(h[0]);
    float2 f1 = __half22float2(h[1]);
    float2 f2 = __half22float2(h[2]);
    float2 f3 = __half22float2(h[3]);
    acc0 += f0.x; acc1 += f0.y;
    acc2 += f1.x; acc3 += f1.y;
    acc4 += f2.x; acc5 += f2.y;
    acc6 += f3.x; acc7 += f3.y;
  }
  if (valid) {
    float dgc = fmaxf((float)dg, 1.0f);
    float4 xa = *(const float4*)&x[w * DF + co];
    float4 xb = *(const float4*)&x[w * DF + co + 4];
    float xs[8] = {xa.x, xa.y, xa.z, xa.w, xb.x, xb.y, xb.z, xb.w};
    float ac[8] = {acc0, acc1, acc2, acc3, acc4, acc5, acc6, acc7};
    float o[8];
#pragma unroll
    for (int k = 0; k < 8; ++k) {
      float s = sqrtf(ac[k] / dgc + EPSF);
      o[k] = xs[k] / s;
      if (isinf(o[k])) o[k] = xs[k];
    }
    float4 oa = {o[0], o[1], o[2], o[3]};
    float4 ob = {o[4], o[5], o[6], o[7]};
    *(float4*)&out[w * DF + co] = oa;
    *(float4*)&out[w * DF + co + 4] = ob;
  }
}

extern "C" void kernel_launch(void* const* d_in, const int* in_sizes, int n_in,
                              void* d_out, int out_size, void* d_ws, size_t ws_size,
                              hipStream_t stream) {
  const float* x = (const float*)d_in[0];
  const int* ei = (const int*)d_in[1];
  const int n_nodes = in_sizes[0] / DF;
  const int ne = in_sizes[1] / 2;
  const int* ii = ei;       // edge_index[0] : targets (segments)
  const int* jj = ei + ne;  // edge_index[1] : sources (gathered)
  const int nb = (n_nodes + PB - 1) / PB;   // 196 coarse buckets

  // ws layout (16B-aligned segments):
  // gcount[256] | dhist[256] | dcur[256] | bstart[257] | deg[n] | curend[n] |
  // perm[n] | sortedj[ne] | union{ bucketed[nb*CAP], xh[nfeat]+yh[nfeat] }
  char* wsb = (char*)d_ws;
  size_t off = 0;
  auto align16 = [](size_t v) { return (v + 15) & ~(size_t)15; };
  int* gcount = (int*)(wsb + off); off = align16(off + 256 * 4);
  int* dhist  = (int*)(wsb + off); off = align16(off + 256 * 4);
  int* dcur   = (int*)(wsb + off); off = align16(off + 256 * 4);
  int* bstart = (int*)(wsb + off); off = align16(off + 257 * 4);
  int* deg    = (int*)(wsb + off); off = align16(off + (size_t)n_nodes * 4);
  int* curend = (int*)(wsb + off); off = align16(off + (size_t)n_nodes * 4);
  int* perm   = (int*)(wsb + off); off = align16(off + (size_t)n_nodes * 4);
  int* sortedj= (int*)(wsb + off); off = align16(off + (size_t)ne * 4);
  unsigned int* bucketed = (unsigned int*)(wsb + off);
  __half* xh = (__half*)(wsb + off);   // aliased over bucketed (disjoint lifetime)
  const int nfeat = n_nodes * DF;
  __half* yh = xh + nfeat;

  float* out = (float*)d_out;

  // zero gcount + dhist in one shot (adjacent)
  hipMemsetAsync(gcount, 0, 512 * sizeof(int), stream);

  k_passA<<<(ne + CHUNK - 1) / CHUNK, 256, 0, stream>>>(ii, jj, gcount, bucketed, ne, nb);
  k_bprefix<<<1, 256, 0, stream>>>(gcount, bstart, nb);
  k_passB<<<nb, 256, 0, stream>>>(bucketed, gcount, bstart, sortedj, deg, curend, dhist, n_nodes);
  k_dprefix<<<1, 256, 0, stream>>>(dhist, dcur);
  k_dscatter<<<(n_nodes + 255) / 256, 256, 0, stream>>>(deg, dcur, perm, n_nodes);

  // bucketed dead from here; xh/yh live in its space
  k_tohalf<<<(nfeat / 8 + 255) / 256, 256, 0, stream>>>(x, xh, nfeat / 8);

  int nwave = (n_nodes + 15) / 16;           // 16 nodes per wave
  int gblocks = (nwave + 3) / 4;             // 4 waves per 256-thread block
  k_meansq<<<gblocks, 256, 0, stream>>>(perm, sortedj, curend, deg, xh, x, yh, n_nodes);
  k_varfinal<<<gblocks, 256, 0, stream>>>(perm, sortedj, curend, deg, yh, x, out, n_nodes);
}

// Round 6
// 86.908 us; speedup vs baseline: 1.6148x; 1.6148x over previous
//
#include <hip/hip_runtime.h>
#include <hip/hip_fp16.h>
#include <math.h>

#define DF 32
#define EPSF 1e-12f
#define PB 128            // nodes per coarse bucket
#define PB_SHIFT 7
#define NBMAX 512         // max buckets supported (9-bit field)
#define CAP 5120          // edge capacity per bucket (mean ~4092, +16 sigma)
#define CHUNK 4096        // edges per passA block (also floats converted per block)
#define EPT 16            // edges per thread

// ---- Pass A: coarse-bucket edges by target node (coalesced packed writes),
// plus folded f32->fp16 conversion of x (each block converts a 4096-float slice).
// packed record: b(9) | i_local(7) | j(16)   [needs n_nodes <= 65536, nb <= 512]
__global__ __launch_bounds__(256) void k_passA(
    const int* __restrict__ ii, const int* __restrict__ jj,
    const float* __restrict__ x, int* __restrict__ gcount,
    unsigned int* __restrict__ bucketed, __half* __restrict__ xh,
    int ne, int nb, int nfeat) {
  __shared__ int hist[NBMAX];
  __shared__ int histc[NBMAX];
  __shared__ int bb[NBMAX];
  __shared__ int excl_s[NBMAX];
  __shared__ int sc[256];
  __shared__ unsigned int stage[CHUNK];
  int t = threadIdx.x;
  hist[t] = 0; hist[t + 256] = 0;
  __syncthreads();

  int base = blockIdx.x * CHUNK;
  unsigned int pk[EPT];
  int rk[EPT];
#pragma unroll
  for (int k = 0; k < EPT; ++k) {
    int e = base + t + k * 256;
    if (e < ne) {
      int i = ii[e], j = jj[e];
      int b = i >> PB_SHIFT;
      pk[k] = ((unsigned)b << 23) | ((unsigned)(i & (PB - 1)) << 16) | (unsigned)j;
      rk[k] = atomicAdd(&hist[b], 1);
    } else {
      rk[k] = -1;
    }
  }

  // folded tohalf: convert this block's 4096-float slice (512 float8 chunks)
  {
    int base8 = blockIdx.x * (CHUNK / 8);
#pragma unroll
    for (int r = 0; r < 2; ++r) {
      int p8 = base8 + r * 256 + t;
      if (p8 * 8 < nfeat) {
        float4 a = ((const float4*)x)[2 * p8];
        float4 bq = ((const float4*)x)[2 * p8 + 1];
        union { __half2 h[4]; float4 f; } u;
        u.h[0] = __floats2half2_rn(a.x, a.y);
        u.h[1] = __floats2half2_rn(a.z, a.w);
        u.h[2] = __floats2half2_rn(bq.x, bq.y);
        u.h[3] = __floats2half2_rn(bq.z, bq.w);
        ((float4*)xh)[p8] = u.f;
      }
    }
  }
  __syncthreads();
  histc[t] = hist[t]; histc[t + 256] = hist[t + 256];
  __syncthreads();
  // reserve global space per bucket
#pragma unroll
  for (int b = t; b < NBMAX; b += 256) {
    int c = histc[b];
    bb[b] = (b < nb && c > 0) ? atomicAdd(&gcount[b], c) : 0;
  }
  // exclusive elem prefix of histc[0..511] via pair scan
  int a0 = histc[2 * t], a1 = histc[2 * t + 1];
  sc[t] = a0 + a1;
  __syncthreads();
  int pv = sc[t];
  for (int s = 1; s < 256; s <<= 1) {
    int v = 0;
    if (t >= s) v = sc[t - s];
    __syncthreads();
    if (t >= s) sc[t] += v;
    __syncthreads();
  }
  int eP = sc[t] - pv;
  excl_s[2 * t] = eP;
  excl_s[2 * t + 1] = eP + a0;
  __syncthreads();
  // group edges by bucket in LDS staging
#pragma unroll
  for (int k = 0; k < EPT; ++k) {
    if (rk[k] >= 0) {
      int b = pk[k] >> 23;
      stage[excl_s[b] + rk[k]] = pk[k];
    }
  }
  __syncthreads();
  // coalesced write-out: run of each bucket goes to its reserved global range
  int bcnt = ne - base;
  if (bcnt > CHUNK) bcnt = CHUNK;
  for (int p = t; p < bcnt; p += 256) {
    unsigned int v = stage[p];
    int b = v >> 23;
    bucketed[(size_t)b * CAP + bb[b] + (p - excl_s[b])] = v;
  }
}

// ---- Pass B: per coarse bucket: self-computed global prefix, CSR build
// (sortedj + deg + curend), and per-bucket degree-sorted node permutation.
__global__ __launch_bounds__(256) void k_passB(
    const unsigned int* __restrict__ bucketed, const int* __restrict__ gcount,
    int* __restrict__ sortedj, int* __restrict__ deg_g, int* __restrict__ curend_g,
    int* __restrict__ perm, int n_nodes, int nb) {
  __shared__ int sc[256];
  __shared__ int lh[PB];
  __shared__ int lcur[PB];
  __shared__ int dh[PB];
  __shared__ int dcur[PB];
  __shared__ int sgbase;
  int b = blockIdx.x;
  int t = threadIdx.x;

  // self prefix over gcount[0..nb) (pair scan over 512 padded)
  int g0 = (2 * t < nb) ? gcount[2 * t] : 0;
  int g1 = (2 * t + 1 < nb) ? gcount[2 * t + 1] : 0;
  sc[t] = g0 + g1;
  __syncthreads();
  int pv = sc[t];
  for (int s = 1; s < 256; s <<= 1) {
    int v = 0;
    if (t >= s) v = sc[t - s];
    __syncthreads();
    if (t >= s) sc[t] += v;
    __syncthreads();
  }
  if (2 * t == b) sgbase = sc[t] - pv;
  if (2 * t + 1 == b) sgbase = sc[t] - pv + g0;
  if (t < PB) { lh[t] = 0; dh[t] = 0; }
  __syncthreads();
  int gbase = sgbase;
  int cnt = gcount[b];

  // local per-node histogram
  const unsigned int* src = bucketed + (size_t)b * CAP;
  for (int p = t; p < cnt; p += 256) {
    int il = (src[p] >> 16) & (PB - 1);
    atomicAdd(&lh[il], 1);
  }
  __syncthreads();
  // scan lh -> per-node exclusive offset; emit deg/curend; degree histogram
  int a = (t < PB) ? lh[t] : 0;
  if (t < PB) sc[t] = a;
  __syncthreads();
  for (int s = 1; s < PB; s <<= 1) {
    int v = 0;
    if (t < PB && t >= s) v = sc[t - s];
    __syncthreads();
    if (t < PB && t >= s) sc[t] += v;
    __syncthreads();
  }
  int excl = (t < PB) ? sc[t] - a : 0;
  int node = b * PB + t;
  bool nvalid = (t < PB) && (node < n_nodes);
  if (t < PB) lcur[t] = excl;
  if (nvalid) {
    deg_g[node] = a;
    curend_g[node] = gbase + excl + a;
    atomicAdd(&dh[a < PB - 1 ? a : PB - 1], 1);
  }
  __syncthreads();
  // scan dh -> degree-sorted scatter cursors
  int d0 = (t < PB) ? dh[t] : 0;
  if (t < PB) sc[t] = d0;
  __syncthreads();
  for (int s = 1; s < PB; s <<= 1) {
    int v = 0;
    if (t < PB && t >= s) v = sc[t - s];
    __syncthreads();
    if (t < PB && t >= s) sc[t] += v;
    __syncthreads();
  }
  if (t < PB) dcur[t] = sc[t] - d0;
  __syncthreads();
  if (nvalid) {
    int bin = a < PB - 1 ? a : PB - 1;
    int pos = atomicAdd(&dcur[bin], 1);
    perm[b * PB + pos] = node;
  } else if (t < PB) {
    perm[b * PB + t] = -1;   // slots beyond this bucket's valid node count
  }
  __syncthreads();
  // CSR scatter of source indices (16KB window -> L2-local)
  for (int p = t; p < cnt; p += 256) {
    unsigned int v = src[p];
    int il = (v >> 16) & (PB - 1);
    int pos = atomicAdd(&lcur[il], 1);
    sortedj[gbase + pos] = (int)(v & 0xFFFFu);
  }
}

// ---- 16 nodes/wave, 4 lanes/node, lane owns 8 features; neighbor loop
// unrolled x4 with dual accumulators for memory-level parallelism.
// fp16 accumulate; fused (x - mean)^2 -> yh (fp16).
__global__ __launch_bounds__(256) void k_meansq(
    const int* __restrict__ perm, const int* __restrict__ sortedj,
    const int* __restrict__ curend, const int* __restrict__ deg,
    const __half* __restrict__ xh, const float* __restrict__ x,
    __half* __restrict__ yh, int n) {
  int wv = (int)((blockIdx.x * blockDim.x + threadIdx.x) >> 6);
  int lane = threadIdx.x & 63;
  int g = lane >> 2;
  int c = lane & 3;
  int ni = wv * 16 + g;
  int w = perm[ni];
  bool valid = (w >= 0);
  int dg = valid ? deg[w] : 0;
  int end = valid ? curend[w] : 0;
  int start = end - dg;
  int co = c * 8;
  __half2 aA0 = {}, aA1 = {}, aA2 = {}, aA3 = {};
  __half2 aB0 = {}, aB1 = {}, aB2 = {}, aB3 = {};
  int s = start;
  for (; s + 4 <= end; s += 4) {
    int j0 = sortedj[s], j1 = sortedj[s + 1], j2 = sortedj[s + 2], j3 = sortedj[s + 3];
    float4 v0 = *(const float4*)&xh[j0 * DF + co];
    float4 v1 = *(const float4*)&xh[j1 * DF + co];
    float4 v2 = *(const float4*)&xh[j2 * DF + co];
    float4 v3 = *(const float4*)&xh[j3 * DF + co];
    const __half2* h0 = (const __half2*)&v0;
    const __half2* h1 = (const __half2*)&v1;
    const __half2* h2 = (const __half2*)&v2;
    const __half2* h3 = (const __half2*)&v3;
    aA0 = __hadd2(aA0, h0[0]); aA1 = __hadd2(aA1, h0[1]);
    aA2 = __hadd2(aA2, h0[2]); aA3 = __hadd2(aA3, h0[3]);
    aB0 = __hadd2(aB0, h1[0]); aB1 = __hadd2(aB1, h1[1]);
    aB2 = __hadd2(aB2, h1[2]); aB3 = __hadd2(aB3, h1[3]);
    aA0 = __hadd2(aA0, h2[0]); aA1 = __hadd2(aA1, h2[1]);
    aA2 = __hadd2(aA2, h2[2]); aA3 = __hadd2(aA3, h2[3]);
    aB0 = __hadd2(aB0, h3[0]); aB1 = __hadd2(aB1, h3[1]);
    aB2 = __hadd2(aB2, h3[2]); aB3 = __hadd2(aB3, h3[3]);
  }
  for (; s < end; ++s) {
    int j = sortedj[s];
    float4 v = *(const float4*)&xh[j * DF + co];
    const __half2* h = (const __half2*)&v;
    aA0 = __hadd2(aA0, h[0]); aA1 = __hadd2(aA1, h[1]);
    aA2 = __hadd2(aA2, h[2]); aA3 = __hadd2(aA3, h[3]);
  }
  if (valid) {
    __half2 s0 = __hadd2(aA0, aB0), s1 = __hadd2(aA1, aB1);
    __half2 s2 = __hadd2(aA2, aB2), s3 = __hadd2(aA3, aB3);
    float inv = 1.0f / fmaxf((float)dg, 1.0f);
    float2 m0 = __half22float2(s0);
    float2 m1 = __half22float2(s1);
    float2 m2 = __half22float2(s2);
    float2 m3 = __half22float2(s3);
    float4 xa = *(const float4*)&x[w * DF + co];
    float4 xb = *(const float4*)&x[w * DF + co + 4];
    float d0 = xa.x - m0.x * inv;
    float d1 = xa.y - m0.y * inv;
    float d2 = xa.z - m1.x * inv;
    float d3 = xa.w - m1.y * inv;
    float d4 = xb.x - m2.x * inv;
    float d5 = xb.y - m2.y * inv;
    float d6 = xb.z - m3.x * inv;
    float d7 = xb.w - m3.y * inv;
    union { __half2 h[4]; float4 f; } u;
    u.h[0] = __floats2half2_rn(d0 * d0, d1 * d1);
    u.h[1] = __floats2half2_rn(d2 * d2, d3 * d3);
    u.h[2] = __floats2half2_rn(d4 * d4, d5 * d5);
    u.h[3] = __floats2half2_rn(d6 * d6, d7 * d7);
    *(float4*)&yh[w * DF + co] = u.f;
  }
}

// ---- same shape on yh; f32 accumulate (2 sets), unrolled x4; fused epilogue.
__global__ __launch_bounds__(256) void k_varfinal(
    const int* __restrict__ perm, const int* __restrict__ sortedj,
    const int* __restrict__ curend, const int* __restrict__ deg,
    const __half* __restrict__ yh, const float* __restrict__ x,
    float* __restrict__ out, int n) {
  int wv = (int)((blockIdx.x * blockDim.x + threadIdx.x) >> 6);
  int lane = threadIdx.x & 63;
  int g = lane >> 2;
  int c = lane & 3;
  int ni = wv * 16 + g;
  int w = perm[ni];
  bool valid = (w >= 0);
  int dg = valid ? deg[w] : 0;
  int end = valid ? curend[w] : 0;
  int start = end - dg;
  int co = c * 8;
  float accA[8], accB[8];
#pragma unroll
  for (int k = 0; k < 8; ++k) { accA[k] = 0.f; accB[k] = 0.f; }
  int s = start;
  for (; s + 4 <= end; s += 4) {
    int j0 = sortedj[s], j1 = sortedj[s + 1], j2 = sortedj[s + 2], j3 = sortedj[s + 3];
    float4 v0 = *(const float4*)&yh[j0 * DF + co];
    float4 v1 = *(const float4*)&yh[j1 * DF + co];
    float4 v2 = *(const float4*)&yh[j2 * DF + co];
    float4 v3 = *(const float4*)&yh[j3 * DF + co];
    const __half2* h0 = (const __half2*)&v0;
    const __half2* h1 = (const __half2*)&v1;
    const __half2* h2 = (const __half2*)&v2;
    const __half2* h3 = (const __half2*)&v3;
#pragma unroll
    for (int k = 0; k < 4; ++k) {
      float2 f0 = __half22float2(h0[k]);
      float2 f1 = __half22float2(h1[k]);
      float2 f2 = __half22float2(h2[k]);
      float2 f3 = __half22float2(h3[k]);
      accA[2 * k]     += f0.x + f2.x;
      accA[2 * k + 1] += f0.y + f2.y;
      accB[2 * k]     += f1.x + f3.x;
      accB[2 * k + 1] += f1.y + f3.y;
    }
  }
  for (; s < end; ++s) {
    int j = sortedj[s];
    float4 v = *(const float4*)&yh[j * DF + co];
    const __half2* h = (const __half2*)&v;
#pragma unroll
    for (int k = 0; k < 4; ++k) {
      float2 f = __half22float2(h[k]);
      accA[2 * k]     += f.x;
      accA[2 * k + 1] += f.y;
    }
  }
  if (valid) {
    float dgc = fmaxf((float)dg, 1.0f);
    float4 xa = *(const float4*)&x[w * DF + co];
    float4 xb = *(const float4*)&x[w * DF + co + 4];
    float xs[8] = {xa.x, xa.y, xa.z, xa.w, xb.x, xb.y, xb.z, xb.w};
    float o[8];
#pragma unroll
    for (int k = 0; k < 8; ++k) {
      float sq = sqrtf((accA[k] + accB[k]) / dgc + EPSF);
      o[k] = xs[k] / sq;
      if (isinf(o[k])) o[k] = xs[k];
    }
    float4 oa = {o[0], o[1], o[2], o[3]};
    float4 ob = {o[4], o[5], o[6], o[7]};
    *(float4*)&out[w * DF + co] = oa;
    *(float4*)&out[w * DF + co + 4] = ob;
  }
}

extern "C" void kernel_launch(void* const* d_in, const int* in_sizes, int n_in,
                              void* d_out, int out_size, void* d_ws, size_t ws_size,
                              hipStream_t stream) {
  const float* x = (const float*)d_in[0];
  const int* ei = (const int*)d_in[1];
  const int n_nodes = in_sizes[0] / DF;
  const int ne = in_sizes[1] / 2;
  const int* ii = ei;       // edge_index[0] : targets (segments)
  const int* jj = ei + ne;  // edge_index[1] : sources (gathered)
  const int nb = (n_nodes + PB - 1) / PB;   // 391 coarse buckets
  const int nfeat = n_nodes * DF;
  const int nperm = nb * PB;

  // ws layout (256 MiB available — no aliasing needed):
  // gcount[512] | deg[n] | curend[n] | perm[nperm] | sortedj[ne] |
  // bucketed[nb*CAP] | xh[nfeat] | yh[nfeat]
  char* wsb = (char*)d_ws;
  size_t off = 0;
  auto align16 = [](size_t v) { return (v + 15) & ~(size_t)15; };
  int* gcount = (int*)(wsb + off); off = align16(off + NBMAX * 4);
  int* deg    = (int*)(wsb + off); off = align16(off + (size_t)n_nodes * 4);
  int* curend = (int*)(wsb + off); off = align16(off + (size_t)n_nodes * 4);
  int* perm   = (int*)(wsb + off); off = align16(off + (size_t)nperm * 4);
  int* sortedj= (int*)(wsb + off); off = align16(off + (size_t)ne * 4);
  unsigned int* bucketed = (unsigned int*)(wsb + off);
  off = align16(off + (size_t)nb * CAP * 4);
  __half* xh = (__half*)(wsb + off); off = align16(off + (size_t)nfeat * 2);
  __half* yh = (__half*)(wsb + off);

  float* out = (float*)d_out;

  hipMemsetAsync(gcount, 0, NBMAX * sizeof(int), stream);

  int nblkA = (ne + CHUNK - 1) / CHUNK;
  int nblkF = (nfeat + CHUNK - 1) / CHUNK;
  if (nblkF > nblkA) nblkA = nblkF;
  k_passA<<<nblkA, 256, 0, stream>>>(ii, jj, x, gcount, bucketed, xh, ne, nb, nfeat);
  k_passB<<<nb, 256, 0, stream>>>(bucketed, gcount, sortedj, deg, curend, perm, n_nodes, nb);

  int gblocks = nperm / 64;   // 4 waves/block, 16 nodes/wave
  k_meansq<<<gblocks, 256, 0, stream>>>(perm, sortedj, curend, deg, xh, x, yh, n_nodes);
  k_varfinal<<<gblocks, 256, 0, stream>>>(perm, sortedj, curend, deg, yh, x, out, n_nodes);
}